// Round 12
// baseline (194.562 us; speedup 1.0000x reference)
//
#include <hip/hip_runtime.h>

#define Bsz 64
#define Lsz 4096
#define Dsz 512
#define Hsz 512
#define Usz 256
#define LT  64
#define NLB (Lsz / LT)          // 64 L-tiles per batch -> 4096 blocks

typedef __attribute__((ext_vector_type(8))) short s8v;     // bf16x8 MFMA frag
typedef __attribute__((ext_vector_type(4))) float f4v;
typedef __attribute__((ext_vector_type(8))) unsigned short u16x8;

// XOR swizzle on a [64][512]-short row: 16B slot ^= row&7 (bijective, b128-aligned)
#define SW(r, c) (((((c) >> 3) ^ ((r) & 7)) << 3) | ((c) & 7))

__device__ __forceinline__ unsigned short f2bf(float f) {
    unsigned int u = __float_as_uint(f);
    u += 0x7FFFu + ((u >> 16) & 1u);   // RNE
    return (unsigned short)(u >> 16);
}
__device__ __forceinline__ float bf2f(unsigned int lo16) {
    return __uint_as_float(lo16 << 16);
}
__device__ __forceinline__ void barrier_lds() {
    asm volatile("s_waitcnt lgkmcnt(0)" ::: "memory");
    __builtin_amdgcn_s_barrier();
}

// ws layout
//   [0,     256K)      : W1T bf16 [256][512]
//   [256K,  512K)      : hp_part f32 [4][64][256]
//   [512K, 1536K)      : el_arr f32 [64][4096]
//   [1536K, +256B)     : den f32 [64]
//   [1536K+256, +128K) : ctx_acc f32 [64][512]

// blocks 0..31: W1->W1T transpose via LDS. 32..287: hproj split-K. 288..351: zero acc.
__global__ __launch_bounds__(256) void k_prep(const float* __restrict__ W1,
                                              const float* __restrict__ hidden,
                                              const float* __restrict__ W2,
                                              unsigned short* __restrict__ W1T,
                                              float* __restrict__ hp_part,
                                              float* __restrict__ den,
                                              float* __restrict__ ctx_acc) {
    int blk = blockIdx.x, tid = threadIdx.x;
    if (blk < 32) {
        __shared__ unsigned short Lt[64][72];
        int kb = blk >> 2, ub = blk & 3;
        {
            int rr = tid >> 2, c16 = (tid & 3) * 16;
            const float* src = W1 + (size_t)(kb * 64 + rr) * Usz + ub * 64 + c16;
            f4v v0 = *reinterpret_cast<const f4v*>(src);
            f4v v1 = *reinterpret_cast<const f4v*>(src + 4);
            f4v v2 = *reinterpret_cast<const f4v*>(src + 8);
            f4v v3 = *reinterpret_cast<const f4v*>(src + 12);
            u16x8 o0 = { f2bf(v0.x), f2bf(v0.y), f2bf(v0.z), f2bf(v0.w),
                         f2bf(v1.x), f2bf(v1.y), f2bf(v1.z), f2bf(v1.w) };
            u16x8 o1 = { f2bf(v2.x), f2bf(v2.y), f2bf(v2.z), f2bf(v2.w),
                         f2bf(v3.x), f2bf(v3.y), f2bf(v3.z), f2bf(v3.w) };
            *reinterpret_cast<u16x8*>(&Lt[rr][c16])     = o0;
            *reinterpret_cast<u16x8*>(&Lt[rr][c16 + 8]) = o1;
        }
        __syncthreads();
        {
            int ur = tid >> 2, k16 = (tid & 3) * 16;
            u16x8 o0, o1;
#pragma unroll
            for (int i = 0; i < 8; ++i) o0[i] = Lt[k16 + i][ur];
#pragma unroll
            for (int i = 0; i < 8; ++i) o1[i] = Lt[k16 + 8 + i][ur];
            unsigned short* dst = W1T + (size_t)(ub * 64 + ur) * Dsz + kb * 64 + k16;
            *reinterpret_cast<u16x8*>(dst)     = o0;
            *reinterpret_cast<u16x8*>(dst + 8) = o1;
        }
    } else if (blk < 288) {
        int idx = blk - 32;
        int kq = idx >> 6, b = idx & 63;
        const float* hrow = hidden + (size_t)b * Hsz + kq * 128;
        const float* w2p  = W2 + (size_t)(kq * 128) * Usz + tid;
        float a0 = 0.f, a1 = 0.f, a2 = 0.f, a3 = 0.f;
#pragma unroll 8
        for (int k = 0; k < 128; k += 4) {
            a0 = fmaf(hrow[k + 0], w2p[(size_t)(k + 0) * Usz], a0);
            a1 = fmaf(hrow[k + 1], w2p[(size_t)(k + 1) * Usz], a1);
            a2 = fmaf(hrow[k + 2], w2p[(size_t)(k + 2) * Usz], a2);
            a3 = fmaf(hrow[k + 3], w2p[(size_t)(k + 3) * Usz], a3);
        }
        hp_part[((size_t)kq * Bsz + b) * Usz + tid] = (a0 + a1) + (a2 + a3);
    } else {
        int b = blk - 288;
        if (tid == 0) den[b] = 0.f;
        ctx_acc[b * Dsz + tid] = 0.f;
        ctx_acc[b * Dsz + 256 + tid] = 0.f;
    }
}

// 4096 blocks x 512 thr (8 waves), 2 blocks/CU. Block (b,lb): one 64-row tile.
// XOR-swizzled [64][512] tile (conflict-free b128 GEMM reads) + depth-2 chunk
// ring: iter c issues loads chunk c+2, GEMMs chunk c, writes chunk c+1 (loaded
// a full chunk earlier -> zero vmcnt stall). One lgkm-only barrier per chunk.
__global__ void __launch_bounds__(512)
__attribute__((amdgpu_waves_per_eu(4, 4))) k_score_ctx(
    const float* __restrict__ feat, const unsigned short* __restrict__ W1T,
    const float* __restrict__ hp_part, const float* __restrict__ W1b,
    const float* __restrict__ W2b, const float* __restrict__ Vk,
    const float* __restrict__ Vb, float* __restrict__ el_arr,
    float* __restrict__ den, float* __restrict__ ctx_acc)
{
    __shared__ __align__(16) unsigned short A[LT][Dsz];  // 64 KiB, swizzled
    __shared__ float hp[Usz], vv[Usz];
    __shared__ float spart[8][LT];
    __shared__ float el[LT];
    __shared__ float pc[2][Dsz];

    const int tid  = threadIdx.x;
    const int w    = tid >> 6;
    const int lane = tid & 63;
    const int lr   = lane & 15;
    const int lg   = lane >> 4;
    const int b    = blockIdx.x >> 6;
    const int lb   = blockIdx.x & 63;
    const int l0   = lb * LT;

    const int srow = tid >> 3;            // 0..63
    const int sfc  = (tid & 7) * 16;      // float col within a 128-float chunk
    const float* fb = feat + ((size_t)b * Lsz + l0 + srow) * Dsz + sfc;

    // ---- prologue: issue chunk0 + chunk1 loads FIRST (vmcnt FIFO head) ----
    f4v st[2][4];
#pragma unroll
    for (int i = 0; i < 4; ++i) st[0][i] = *reinterpret_cast<const f4v*>(fb + i * 4);
#pragma unroll
    for (int i = 0; i < 4; ++i) st[1][i] = *reinterpret_cast<const f4v*>(fb + 128 + i * 4);
    __builtin_amdgcn_sched_barrier(0);

    if (tid < Usz) {
        const float* hpb = hp_part + (size_t)b * Usz + tid;
        hp[tid] = (hpb[0] + hpb[Bsz * Usz]) + (hpb[2 * Bsz * Usz] + hpb[3 * Bsz * Usz])
                + W1b[tid] + W2b[tid];
        vv[tid] = Vk[tid];
    }
    {   // write chunk 0
        u16x8 o0 = { f2bf(st[0][0].x), f2bf(st[0][0].y), f2bf(st[0][0].z), f2bf(st[0][0].w),
                     f2bf(st[0][1].x), f2bf(st[0][1].y), f2bf(st[0][1].z), f2bf(st[0][1].w) };
        u16x8 o1 = { f2bf(st[0][2].x), f2bf(st[0][2].y), f2bf(st[0][2].z), f2bf(st[0][2].w),
                     f2bf(st[0][3].x), f2bf(st[0][3].y), f2bf(st[0][3].z), f2bf(st[0][3].w) };
        *reinterpret_cast<u16x8*>(&A[srow][SW(srow, sfc)])     = o0;
        *reinterpret_cast<u16x8*>(&A[srow][SW(srow, sfc + 8)]) = o1;
    }
    barrier_lds();

    // ---- pipelined GEMM over 4 K-chunks ----
    const unsigned short* bp0 = W1T + (size_t)(w * 32 + lr) * Dsz + lg * 8;
    const unsigned short* bp1 = bp0 + 16 * Dsz;
    f4v acc[4][2];
#pragma unroll
    for (int mf = 0; mf < 4; ++mf) {
        acc[mf][0] = (f4v){0.f, 0.f, 0.f, 0.f};
        acc[mf][1] = (f4v){0.f, 0.f, 0.f, 0.f};
    }

#pragma unroll
    for (int c = 0; c < 4; ++c) {
        // (1) B-frags for chunk c (L2) — first in FIFO this iteration
        s8v bq[4][2];
#pragma unroll
        for (int k = 0; k < 4; ++k) {
            bq[k][0] = *reinterpret_cast<const s8v*>(bp0 + (c * 4 + k) * 32);
            bq[k][1] = *reinterpret_cast<const s8v*>(bp1 + (c * 4 + k) * 32);
        }
        __builtin_amdgcn_sched_barrier(0);
        // (2) issue chunk c+2 feature loads (HBM) — in flight for a full chunk
        if (c < 2) {
#pragma unroll
            for (int i = 0; i < 4; ++i)
                st[c & 1][i] = *reinterpret_cast<const f4v*>(fb + (c + 2) * 128 + i * 4);
        }
        __builtin_amdgcn_sched_barrier(0);
        // (3) GEMM chunk c from swizzled LDS
#pragma unroll
        for (int k = 0; k < 4; ++k) {
            const int kof = (c * 4 + k) * 32 + lg * 8;
#pragma unroll
            for (int mf = 0; mf < 4; ++mf) {
                const int row = mf * 16 + lr;
                s8v a = *reinterpret_cast<const s8v*>(&A[row][SW(row, kof)]);
                acc[mf][0] = __builtin_amdgcn_mfma_f32_16x16x32_bf16(a, bq[k][0], acc[mf][0], 0, 0, 0);
                acc[mf][1] = __builtin_amdgcn_mfma_f32_16x16x32_bf16(a, bq[k][1], acc[mf][1], 0, 0, 0);
            }
        }
        __builtin_amdgcn_sched_barrier(0);
        // (4) write chunk c+1 (loaded one full chunk ago -> no vmcnt stall)
        if (c < 3) {
            const int cc = (c + 1) * 128 + sfc;
            const f4v* s = st[(c + 1) & 1];
            u16x8 o0 = { f2bf(s[0].x), f2bf(s[0].y), f2bf(s[0].z), f2bf(s[0].w),
                         f2bf(s[1].x), f2bf(s[1].y), f2bf(s[1].z), f2bf(s[1].w) };
            u16x8 o1 = { f2bf(s[2].x), f2bf(s[2].y), f2bf(s[2].z), f2bf(s[2].w),
                         f2bf(s[3].x), f2bf(s[3].y), f2bf(s[3].z), f2bf(s[3].w) };
            *reinterpret_cast<u16x8*>(&A[srow][SW(srow, cc)])     = o0;
            *reinterpret_cast<u16x8*>(&A[srow][SW(srow, cc + 8)]) = o1;
            barrier_lds();
        }
    }

    // ---- epilogue: per-row sum of tanh(x)*V over this wave's 32 cols ----
    {
        float rs[4][4];
#pragma unroll
        for (int mf = 0; mf < 4; ++mf)
#pragma unroll
            for (int r = 0; r < 4; ++r) rs[mf][r] = 0.f;
#pragma unroll
        for (int mf = 0; mf < 4; ++mf)
#pragma unroll
            for (int nf = 0; nf < 2; ++nf) {
                int col = w * 32 + nf * 16 + lr;
                float hpv = hp[col], vvv = vv[col];
#pragma unroll
                for (int r = 0; r < 4; ++r) {
                    float x = acc[mf][nf][r] + hpv;
                    float e = __expf(2.f * x);
                    rs[mf][r] = fmaf(1.f - 2.f / (e + 1.f), vvv, rs[mf][r]);
                }
            }
#pragma unroll
        for (int off = 1; off < 16; off <<= 1)
#pragma unroll
            for (int mf = 0; mf < 4; ++mf)
#pragma unroll
                for (int r = 0; r < 4; ++r)
                    rs[mf][r] += __shfl_xor(rs[mf][r], off, 64);
        if (lr == 0)
#pragma unroll
            for (int mf = 0; mf < 4; ++mf)
#pragma unroll
                for (int r = 0; r < 4; ++r)
                    spart[w][mf * 16 + lg * 4 + r] = rs[mf][r];
    }
    barrier_lds();

    // ---- scores -> exp -> denominator (wave 0) ----
    if (tid < LT) {
        float s = Vb[0];
#pragma unroll
        for (int ww = 0; ww < 8; ++ww) s += spart[ww][tid];
        float e = __expf(s);
        el[tid] = e;
        el_arr[(size_t)b * Lsz + l0 + tid] = e;
        float es = e;
#pragma unroll
        for (int off = 1; off < 64; off <<= 1) es += __shfl_xor(es, off, 64);
        if (tid == 0) atomicAdd(&den[b], es);
    }
    barrier_lds();

    // ---- context: swizzled u32-pair reads, two row-halves, pc-reduce ----
    {
        const int qr = tid >> 8;            // 0..1 (row half)
        const int d0 = (tid & 255) * 2;
        float a0 = 0.f, a1 = 0.f;
#pragma unroll 8
        for (int li = 0; li < 32; ++li) {
            int l = qr * 32 + li;
            unsigned int pk = *reinterpret_cast<const unsigned int*>(&A[l][SW(l, d0)]);
            float e = el[l];
            a0 = fmaf(e, bf2f(pk & 0xFFFFu), a0);
            a1 = fmaf(e, bf2f(pk >> 16), a1);
        }
        pc[qr][d0]     = a0;
        pc[qr][d0 + 1] = a1;
    }
    barrier_lds();
    atomicAdd(&ctx_acc[b * Dsz + tid], pc[0][tid] + pc[1][tid]);
}

__global__ __launch_bounds__(256) void k_finalize(const float* __restrict__ el_arr,
                                                  const float* __restrict__ den,
                                                  const float* __restrict__ ctx_acc,
                                                  float* __restrict__ ctx,
                                                  float* __restrict__ wout) {
    int blk = blockIdx.x, tid = threadIdx.x;
    int b = blk >> 2, q = blk & 3;
    float inv = 1.f / den[b];
    size_t base = (size_t)b * Lsz + q * 1024 + tid * 4;
    f4v e4 = *reinterpret_cast<const f4v*>(&el_arr[base]);
    f4v w4 = { e4.x * inv, e4.y * inv, e4.z * inv, e4.w * inv };
    *reinterpret_cast<f4v*>(&wout[base]) = w4;
    if (tid < 128) {
        int d = q * 128 + tid;
        ctx[(size_t)b * Dsz + d] = ctx_acc[b * Dsz + d] * inv;
    }
}

extern "C" void kernel_launch(void* const* d_in, const int* in_sizes, int n_in,
                              void* d_out, int out_size, void* d_ws, size_t ws_size,
                              hipStream_t stream) {
    const float* feat   = (const float*)d_in[0];
    const float* hidden = (const float*)d_in[1];
    const float* W1     = (const float*)d_in[2];
    const float* W1b    = (const float*)d_in[3];
    const float* W2     = (const float*)d_in[4];
    const float* W2b    = (const float*)d_in[5];
    const float* Vk     = (const float*)d_in[6];
    const float* Vb     = (const float*)d_in[7];

    unsigned short* w1t = (unsigned short*)d_ws;
    float* hp_part = (float*)((char*)d_ws + 256 * 1024);
    float* el_arr  = (float*)((char*)d_ws + 512 * 1024);
    float* den     = (float*)((char*)d_ws + 1536 * 1024);
    float* ctx_acc = (float*)((char*)d_ws + 1536 * 1024 + 256);

    float* ctx  = (float*)d_out;              // [64, 512]
    float* wout = ctx + Bsz * Dsz;            // [64, 4096, 1]

    k_prep<<<352, 256, 0, stream>>>(W1, hidden, W2, w1t, hp_part, den, ctx_acc);
    k_score_ctx<<<Bsz * NLB, 512, 0, stream>>>(feat, w1t, hp_part, W1b, W2b,
                                               Vk, Vb, el_arr, den, ctx_acc);
    k_finalize<<<Bsz * 4, 256, 0, stream>>>(el_arr, den, ctx_acc, ctx, wout);
}